// Round 7
// baseline (314.675 us; speedup 1.0000x reference)
//
#include <hip/hip_runtime.h>
#include <cstdint>
#include <cstddef>

typedef __attribute__((ext_vector_type(8))) __bf16 bf16x8;
typedef __attribute__((ext_vector_type(8))) unsigned short us8;
typedef __attribute__((ext_vector_type(4))) unsigned short us4;
typedef __attribute__((ext_vector_type(4))) float f32x4;
typedef __attribute__((ext_vector_type(16))) float f32x16;

#define DEVI static __device__ __forceinline__

DEVI unsigned short f2bf(float f) {
  union { float f; unsigned u; } v; v.f = f;
  unsigned r = v.u + 0x7fffu + ((v.u >> 16) & 1u);
  return (unsigned short)(r >> 16);
}

DEVI f32x4 mfma16(us8 a, us8 b, f32x4 c) {
  return __builtin_amdgcn_mfma_f32_16x16x32_bf16(
      __builtin_bit_cast(bf16x8, a), __builtin_bit_cast(bf16x8, b), c, 0, 0, 0);
}

DEVI f32x16 mfma32(us8 a, us8 b, f32x16 c) {
  return __builtin_amdgcn_mfma_f32_32x32x16_bf16(
      __builtin_bit_cast(bf16x8, a), __builtin_bit_cast(bf16x8, b), c, 0, 0, 0);
}

DEVI f32x4 fzero4() { f32x4 v = {0.f, 0.f, 0.f, 0.f}; return v; }

// tanh-form GELU: ~9 VALU ops vs erff's ~20+. |err| < 3e-3 abs.
DEVI float gelu_f(float v) {
  float z = 0.7978845608f * v * (1.f + 0.044715f * v * v);
  float e = __expf(2.f * z);
  float r = 1.f / (e + 1.f);
  return v * (1.f - r);
}

DEVI unsigned pkbf(float lo, float hi) {
  unsigned r;
  asm("v_cvt_pk_bf16_f32 %0, %1, %2" : "=v"(r) : "v"(lo), "v"(hi));
  return r;
}

DEVI void pswap(unsigned& x, unsigned& y) {
  asm volatile("v_permlane32_swap_b32 %0, %1" : "+v"(x), "+v"(y));
}

// global -> LDS direct copy, 16 B per lane.
DEVI void gload16(const unsigned short* g, unsigned short* l) {
  __builtin_amdgcn_global_load_lds(
      (const __attribute__((address_space(1))) unsigned int*)g,
      (__attribute__((address_space(3))) unsigned int*)l, 16, 0, 0);
}

// counted vmcnt wait + scheduling fence (rule #18)
template <int N>
DEVI void wait_vm() {
  if constexpr (N == 0) asm volatile("s_waitcnt vmcnt(0)" ::: "memory");
  else if constexpr (N == 4) asm volatile("s_waitcnt vmcnt(4)" ::: "memory");
  else if constexpr (N == 6) asm volatile("s_waitcnt vmcnt(6)" ::: "memory");
  else if constexpr (N == 8) asm volatile("s_waitcnt vmcnt(8)" ::: "memory");
  __builtin_amdgcn_sched_barrier(0);
}

// ---------------------------------------------------------------------------
// Weight transpose + fp32->bf16 cast: w[K][N] -> wt[N][K]
// ---------------------------------------------------------------------------
__global__ __launch_bounds__(256)
void transpose_w(const float* __restrict__ w, unsigned short* __restrict__ wt,
                 int K, int N) {
  __shared__ unsigned short tile[64][65];
  const int t = threadIdx.x;
  const int kb = blockIdx.x * 64, nb = blockIdx.y * 64;
#pragma unroll
  for (int i = 0; i < 4; ++i) {
    int r = i * 16 + (t >> 4);
    int c = (t & 15) * 4;
    float4 v = *(const float4*)(w + (size_t)(kb + r) * N + nb + c);
    tile[r][c + 0] = f2bf(v.x);
    tile[r][c + 1] = f2bf(v.y);
    tile[r][c + 2] = f2bf(v.z);
    tile[r][c + 3] = f2bf(v.w);
  }
  __syncthreads();
#pragma unroll
  for (int i = 0; i < 4; ++i) {
    int n = i * 16 + (t >> 4);
    int k = (t & 15) * 4;
    us4 o;
    o[0] = tile[k + 0][n];
    o[1] = tile[k + 1][n];
    o[2] = tile[k + 2][n];
    o[3] = tile[k + 3][n];
    *(us4*)(wt + (size_t)(nb + n) * K + kb + k) = o;
  }
}

// ---------------------------------------------------------------------------
// LayerNorm over C=1024, fp32 in -> bf16 out.
// ---------------------------------------------------------------------------
__global__ __launch_bounds__(256)
void ln_kernel(const float* __restrict__ x, const float* __restrict__ g,
               const float* __restrict__ b, unsigned short* __restrict__ o) {
  const int row = blockIdx.x;
  const int tid = threadIdx.x;
  const float* xr = x + (size_t)row * 1024;
  float4 v = *(const float4*)(xr + tid * 4);
  float s = v.x + v.y + v.z + v.w;
  float sq = v.x * v.x + v.y * v.y + v.z * v.z + v.w * v.w;
#pragma unroll
  for (int m = 1; m < 64; m <<= 1) {
    s += __shfl_xor(s, m, 64);
    sq += __shfl_xor(sq, m, 64);
  }
  __shared__ float ss[4], ssq[4];
  const int wid = tid >> 6, lane = tid & 63;
  if (lane == 0) { ss[wid] = s; ssq[wid] = sq; }
  __syncthreads();
  s = ss[0] + ss[1] + ss[2] + ss[3];
  sq = ssq[0] + ssq[1] + ssq[2] + ssq[3];
  const float mu = s * (1.f / 1024.f);
  const float var = sq * (1.f / 1024.f) - mu * mu;
  const float rstd = rsqrtf(var + 1e-5f);
  const int c = tid * 4;
  float4 gv = *(const float4*)(g + c);
  float4 bv = *(const float4*)(b + c);
  us4 ov;
  ov[0] = f2bf((v.x - mu) * rstd * gv.x + bv.x);
  ov[1] = f2bf((v.y - mu) * rstd * gv.y + bv.y);
  ov[2] = f2bf((v.z - mu) * rstd * gv.z + bv.z);
  ov[3] = f2bf((v.w - mu) * rstd * gv.w + bv.w);
  *(us4*)(o + (size_t)row * 1024 + c) = ov;
}

// ---------------------------------------------------------------------------
// DynamicPosBias MLP -> posT[16][3969] (f32). One wave per row.
// ---------------------------------------------------------------------------
DEVI float pos_layer(float p, const float* __restrict__ g,
                     const float* __restrict__ be, const float* __restrict__ w,
                     const float* __restrict__ bb, int lane) {
  float s = p, sq = p * p;
#pragma unroll
  for (int m = 1; m < 64; m <<= 1) {
    s += __shfl_xor(s, m, 64);
    sq += __shfl_xor(sq, m, 64);
  }
  float mu = s * (1.f / 64.f);
  float var = sq * (1.f / 64.f) - mu * mu;
  float rstd = rsqrtf(var + 1e-5f);
  float y = fmaxf((p - mu) * rstd * g[lane] + be[lane], 0.f);
  float o = bb[lane];
  for (int k = 0; k < 64; ++k) {
    float yk = __shfl(y, k, 64);
    o += yk * w[k * 64 + lane];
  }
  return o;
}

__global__ __launch_bounds__(256)
void pos_mlp(const float* __restrict__ pp_w, const float* __restrict__ pp_b,
             const float* __restrict__ g1, const float* __restrict__ b1,
             const float* __restrict__ w1, const float* __restrict__ bb1,
             const float* __restrict__ g2, const float* __restrict__ b2,
             const float* __restrict__ w2, const float* __restrict__ bb2,
             const float* __restrict__ g3, const float* __restrict__ b3,
             const float* __restrict__ w3, const float* __restrict__ bb3,
             float* __restrict__ posT) {
  const int wid = threadIdx.x >> 6, lane = threadIdx.x & 63;
  const int row = blockIdx.x * 4 + wid;
  if (row >= 3969) return;
  const float bh = (float)(row / 63) - 31.f;
  const float bw = (float)(row % 63) - 31.f;
  float p = bh * pp_w[lane] + bw * pp_w[64 + lane] + pp_b[lane];
  p = pos_layer(p, g1, b1, w1, bb1, lane);
  p = pos_layer(p, g2, b2, w2, bb2, lane);
  float s = p, sq = p * p;
#pragma unroll
  for (int m = 1; m < 64; m <<= 1) {
    s += __shfl_xor(s, m, 64);
    sq += __shfl_xor(sq, m, 64);
  }
  float mu = s * (1.f / 64.f);
  float var = sq * (1.f / 64.f) - mu * mu;
  float rstd = rsqrtf(var + 1e-5f);
  float y = fmaxf((p - mu) * rstd * g3[lane] + b3[lane], 0.f);
  float o = 0.f;
  for (int k = 0; k < 64; ++k) {
    float yk = __shfl(y, k, 64);
    o += yk * w3[k * 16 + (lane & 15)];
  }
  if (lane < 16) posT[(size_t)lane * 3969 + row] = o + bb3[lane];
}

// ---------------------------------------------------------------------------
// GEMM, triple-buffered counted-vmcnt pipeline (T3+T4) + LDS XOR swizzle (T2).
// C[M,N] = A[M,K](bf16) @ Bt[N,K]^T, fp32 accum. Tile BM x BN, 4 waves, BK=64.
// Stage kb+2 each iter; end-of-iter waits vmcnt(L) (newest stage in flight),
// raw s_barrier, sched_barrier fences. LDS swizzle: linear gload_lds dest +
// pre-swizzled global source chunk (c ^ row&7) + XOR'd ds_read col.
// ---------------------------------------------------------------------------
template <int BM, int BN, bool HAS_BIAS, bool GELU_, bool HAS_RES,
          bool OUT_BF16, bool OUT_F32>
__global__ __launch_bounds__(256)
void gemm_bt(const unsigned short* __restrict__ A,
             const unsigned short* __restrict__ Bt,
             const float* __restrict__ bias, const float* __restrict__ res,
             unsigned short* __restrict__ outb, float* __restrict__ outf,
             int M, int N, int K) {
  constexpr int MT = BM / 32;
  constexpr int NT = BN / 32;
  constexpr int LPS = (BM + BN) / 32;  // gload16 per thread per stage
  __shared__ unsigned short As[3][BM * 64];
  __shared__ unsigned short Bs[3][BN * 64];
  const int tid = threadIdx.x;
  const int lane = tid & 63;
  const int wid = tid >> 6;
  const int lr = lane & 15, lg = lane >> 4;
  const int wr = wid >> 1, wc = wid & 1;
  const int brow = blockIdx.x, bcol = blockIdx.y;

  f32x4 acc[MT][NT];
#pragma unroll
  for (int mt = 0; mt < MT; ++mt)
#pragma unroll
    for (int nt = 0; nt < NT; ++nt) acc[mt][nt] = fzero4();

  const int srow = wid * 8 + (lane >> 3);
  // pre-swizzled source: lane writing LDS chunk c of row r loads global
  // chunk c ^ (r&7); here r&7 == (lane>>3)&7.
  const int scol = ((lane & 7) ^ ((lane >> 3) & 7)) * 8;
  const unsigned short* Ag = A + (size_t)(brow * BM + srow) * K + scol;
  const unsigned short* Bg = Bt + (size_t)(bcol * BN + srow) * K + scol;

  auto stage = [&](int buf, int kb) {
#pragma unroll
    for (int q = 0; q < BM / 32; ++q)
      gload16(Ag + (size_t)(q * 32) * K + kb * 64,
              &As[buf][(q * 32 + wid * 8) * 64]);
#pragma unroll
    for (int q = 0; q < BN / 32; ++q)
      gload16(Bg + (size_t)(q * 32) * K + kb * 64,
              &Bs[buf][(q * 32 + wid * 8) * 64]);
  };

  const int nkb = K >> 6;
  stage(0, 0);
  stage(1, 1);
  wait_vm<LPS>();  // tile 0 landed; tile 1 may stay in flight
  __builtin_amdgcn_s_barrier();
  __builtin_amdgcn_sched_barrier(0);

  for (int kb = 0; kb < nkb; ++kb) {
    const int cur = kb % 3;
    const bool more = (kb + 2) < nkb;
    if (more) stage((kb + 2) % 3, kb + 2);
#pragma unroll
    for (int ks = 0; ks < 2; ++ks) {
      us8 af[MT], bfr[NT];
#pragma unroll
      for (int mt = 0; mt < MT; ++mt) {
        const int r = wr * (BM / 2) + mt * 16 + lr;
        const int cb = (ks * 64 + lg * 16) ^ ((lr & 7) << 4);
        af[mt] = *(const us8*)((const char*)&As[cur][0] + r * 128 + cb);
      }
#pragma unroll
      for (int nt = 0; nt < NT; ++nt) {
        const int r = wc * (BN / 2) + nt * 16 + lr;
        const int cb = (ks * 64 + lg * 16) ^ ((lr & 7) << 4);
        bfr[nt] = *(const us8*)((const char*)&Bs[cur][0] + r * 128 + cb);
      }
      __builtin_amdgcn_s_setprio(1);
#pragma unroll
      for (int mt = 0; mt < MT; ++mt)
#pragma unroll
        for (int nt = 0; nt < NT; ++nt)
          acc[mt][nt] = mfma16(af[mt], bfr[nt], acc[mt][nt]);
      __builtin_amdgcn_s_setprio(0);
    }
    // tile kb+1 (issued last iter) must be resident before next compute;
    // the newest stage (kb+2, LPS loads) stays in flight across the barrier.
    if (more) wait_vm<LPS>(); else wait_vm<0>();
    asm volatile("s_waitcnt lgkmcnt(0)" ::: "memory");
    __builtin_amdgcn_s_barrier();
    __builtin_amdgcn_sched_barrier(0);
  }

#pragma unroll
  for (int mt = 0; mt < MT; ++mt) {
    const int row = brow * BM + wr * (BM / 2) + mt * 16 + 4 * lg;
#pragma unroll
    for (int nt = 0; nt < NT; ++nt) {
      const int col = bcol * BN + wc * (BN / 2) + nt * 16 + lr;
      float bsv = 0.f;
      if constexpr (HAS_BIAS) bsv = bias[col];
#pragma unroll
      for (int i = 0; i < 4; ++i) {
        float v = acc[mt][nt][i] + bsv;
        if constexpr (GELU_) v = gelu_f(v);
        if constexpr (HAS_RES) v += res[(size_t)(row + i) * N + col];
        if constexpr (OUT_F32) outf[(size_t)(row + i) * N + col] = v;
        if constexpr (OUT_BF16) outb[(size_t)(row + i) * N + col] = f2bf(v);
      }
    }
  }
}

// ---------------------------------------------------------------------------
// Flash attention, swapped-QK^T 32x32 structure (T12) + dynamic pos bias.
// ---------------------------------------------------------------------------
__global__ __launch_bounds__(256)
void attn_kernel(const unsigned short* __restrict__ qkv,
                 const float* __restrict__ posT,
                 unsigned short* __restrict__ attnb) {
  __shared__ unsigned short Ks[64 * 64];  // [k][d], XOR-swizzled rows
  __shared__ unsigned short Vt[64 * 64];  // [d][k], XOR-swizzled rows

  const int tid = threadIdx.x;
  const int wid = tid >> 6;
  const int lane = tid & 63;
  const int ql = lane & 31;
  const int hi = lane >> 5;

  const int p = blockIdx.x;
  const int orig = (p & 7) * 64 + (p >> 3);
  const int b = orig >> 7;
  const int h = (orig >> 3) & 15;
  const int qt = orig & 7;

  const int LDQ = 3072;
  const int qg = qt * 128 + wid * 32 + ql;

  us8 qf[4];
  const unsigned short* qptr =
      qkv + (size_t)(b * 1024 + qg) * LDQ + h * 64 + 8 * hi;
#pragma unroll
  for (int db = 0; db < 4; ++db) qf[db] = *(const us8*)(qptr + db * 16);

  const float* pb = posT + (size_t)h * 3969;
  const int rb_q = ((qg >> 5) + 31) * 63 + (qg & 31) + 31 - 4 * hi;

  f32x16 oacc[2];
#pragma unroll
  for (int r = 0; r < 16; ++r) { oacc[0][r] = 0.f; oacc[1][r] = 0.f; }
  float mreg = -1e30f, lsum = 0.f;

  const int ksr = tid >> 2;
  const int ksc = (tid & 3) * 16;
  const int vk0 = (tid >> 4) * 4;
  const int vd0 = (tid & 15) * 4;

  const unsigned short* kbase = qkv + (size_t)(b * 1024) * LDQ + 1024 + h * 64;
  const unsigned short* vbase = qkv + (size_t)(b * 1024) * LDQ + 2048 + h * 64;

  us8 pk0 = *(const us8*)(kbase + (size_t)ksr * LDQ + ksc);
  us8 pk1 = *(const us8*)(kbase + (size_t)ksr * LDQ + ksc + 8);
  us4 pvv[4];
#pragma unroll
  for (int j = 0; j < 4; ++j)
    pvv[j] = *(const us4*)(vbase + (size_t)(vk0 + j) * LDQ + vd0);

  for (int kt = 0; kt < 16; ++kt) {
    __syncthreads();
    {
      char* ksb = (char*)Ks;
      const int swr = (ksr & 7) << 4;
      *(us8*)(ksb + ksr * 128 + ((ksc * 2) ^ swr)) = pk0;
      *(us8*)(ksb + ksr * 128 + (((ksc + 8) * 2) ^ swr)) = pk1;
      char* vtb = (char*)Vt;
#pragma unroll
      for (int u = 0; u < 4; ++u) {
        us4 w;
        w[0] = pvv[0][u]; w[1] = pvv[1][u]; w[2] = pvv[2][u]; w[3] = pvv[3][u];
        const int d = vd0 + u;
        *(us4*)(vtb + d * 128 + ((vk0 * 2) ^ ((d & 7) << 4))) = w;
      }
    }
    __syncthreads();

    if (kt < 15) {
      const unsigned short* kb2 = kbase + (size_t)((kt + 1) * 64) * LDQ;
      const unsigned short* vb2 = vbase + (size_t)((kt + 1) * 64) * LDQ;
      pk0 = *(const us8*)(kb2 + (size_t)ksr * LDQ + ksc);
      pk1 = *(const us8*)(kb2 + (size_t)ksr * LDQ + ksc + 8);
#pragma unroll
      for (int j = 0; j < 4; ++j)
        pvv[j] = *(const us4*)(vb2 + (size_t)(vk0 + j) * LDQ + vd0);
    }

    f32x16 st0, st1;
#pragma unroll
    for (int r = 0; r < 16; ++r) { st0[r] = 0.f; st1[r] = 0.f; }
    const char* ksb = (const char*)Ks;
    const int kswz = (ql & 7) << 4;
    __builtin_amdgcn_s_setprio(1);
#pragma unroll
    for (int db = 0; db < 4; ++db) {
      const int coff = (db * 32 + 16 * hi) ^ kswz;
      us8 kf0 = *(const us8*)(ksb + ql * 128 + coff);
      us8 kf1 = *(const us8*)(ksb + (32 + ql) * 128 + coff);
      st0 = mfma32(kf0, qf[db], st0);
      st1 = mfma32(kf1, qf[db], st1);
    }
    __builtin_amdgcn_s_setprio(0);

    float sv0[16], sv1[16];
    const float* pb0 = pb + (rb_q - 63 * (2 * kt));
    const float* pb1 = pb0 - 63;
    float mm[16];
#pragma unroll
    for (int r = 0; r < 16; ++r) {
      const int roff = (r & 3) + 8 * (r >> 2);
      float a = st0[r] * 0.125f + pb0[-roff];
      float c = st1[r] * 0.125f + pb1[-roff];
      sv0[r] = a;
      sv1[r] = c;
      mm[r] = fmaxf(a, c);
    }
#pragma unroll
    for (int w = 8; w >= 1; w >>= 1)
#pragma unroll
      for (int r = 0; r < w; ++r) mm[r] = fmaxf(mm[r], mm[r + w]);
    float mx = fmaxf(mreg, mm[0]);
    mx = fmaxf(mx, __shfl_xor(mx, 32, 64));
    const float f = __expf(mreg - mx);
    mreg = mx;

    float ts[16];
#pragma unroll
    for (int r = 0; r < 16; ++r) {
      float e0 = __expf(sv0[r] - mx);
      float e1 = __expf(sv1[r] - mx);
      sv0[r] = e0;
      sv1[r] = e1;
      ts[r] = e0 + e1;
    }
#pragma unroll
    for (int w = 8; w >= 1; w >>= 1)
#pragma unroll
      for (int r = 0; r < w; ++r) ts[r] += ts[r + w];
    lsum = lsum * f + ts[0];
#pragma unroll
    for (int r = 0; r < 16; ++r) { oacc[0][r] *= f; oacc[1][r] *= f; }

    const char* vtb = (const char*)Vt;
    auto pvfrag = [&](const float* sv, int kb) {
      const int B0 = (kb & 1) * 8;
      unsigned a0 = pkbf(sv[B0 + 0], sv[B0 + 1]);
      unsigned a1 = pkbf(sv[B0 + 2], sv[B0 + 3]);
      unsigned b0 = pkbf(sv[B0 + 4], sv[B0 + 5]);
      unsigned b1 = pkbf(sv[B0 + 6], sv[B0 + 7]);
      pswap(a0, b0);
      pswap(a1, b1);
      union { us8 s; unsigned u[4]; } fu;
      fu.u[0] = a0; fu.u[1] = a1; fu.u[2] = b0; fu.u[3] = b1;
      const int coff = (kb * 32 + 16 * hi) ^ kswz;
      us8 vf0 = *(const us8*)(vtb + ql * 128 + coff);
      us8 vf1 = *(const us8*)(vtb + (32 + ql) * 128 + coff);
      __builtin_amdgcn_s_setprio(1);
      oacc[0] = mfma32(vf0, fu.s, oacc[0]);
      oacc[1] = mfma32(vf1, fu.s, oacc[1]);
      __builtin_amdgcn_s_setprio(0);
    };
    pvfrag(sv0, 0);
    pvfrag(sv0, 1);
    pvfrag(sv1, 2);
    pvfrag(sv1, 3);
  }

  lsum += __shfl_xor(lsum, 32, 64);
  const float inv = 1.f / lsum;
  unsigned short* orow = attnb + (size_t)(b * 1024 + qg) * 1024 + h * 64;
#pragma unroll
  for (int dm = 0; dm < 2; ++dm)
#pragma unroll
    for (int r = 0; r < 16; ++r) {
      const int d = dm * 32 + (r & 3) + 8 * (r >> 2) + 4 * hi;
      orow[d] = f2bf(oacc[dm][r] * inv);
    }
}

// ---------------------------------------------------------------------------
// Launcher
// ---------------------------------------------------------------------------
extern "C" void kernel_launch(void* const* d_in, const int* in_sizes, int n_in,
                              void* d_out, int out_size, void* d_ws,
                              size_t ws_size, hipStream_t stream) {
  const float* x = (const float*)d_in[0];
  const float* n1g = (const float*)d_in[1];
  const float* n1b = (const float*)d_in[2];
  const float* q_w = (const float*)d_in[3];
  const float* kv_w = (const float*)d_in[4];
  const float* proj_w = (const float*)d_in[5];
  const float* proj_b = (const float*)d_in[6];
  const float* pp_w = (const float*)d_in[7];
  const float* pp_b = (const float*)d_in[8];
  const float* ln1g = (const float*)d_in[9];
  const float* ln1b = (const float*)d_in[10];
  const float* lin1w = (const float*)d_in[11];
  const float* lin1b = (const float*)d_in[12];
  const float* ln2g = (const float*)d_in[13];
  const float* ln2b = (const float*)d_in[14];
  const float* lin2w = (const float*)d_in[15];
  const float* lin2b = (const float*)d_in[16];
  const float* ln3g = (const float*)d_in[17];
  const float* ln3b = (const float*)d_in[18];
  const float* lin3w = (const float*)d_in[19];
  const float* lin3b = (const float*)d_in[20];
  const float* n2g = (const float*)d_in[21];
  const float* n2b = (const float*)d_in[22];
  const float* fc1_w = (const float*)d_in[23];
  const float* fc1_b = (const float*)d_in[24];
  const float* fc2_w = (const float*)d_in[25];
  const float* fc2_b = (const float*)d_in[26];
  float* out = (float*)d_out;

  char* ws = (char*)d_ws;
  const size_t MB = 1024ull * 1024ull;
  unsigned short* qkvT = (unsigned short*)(ws + 0 * MB);
  unsigned short* projT = (unsigned short*)(ws + 6 * MB);
  unsigned short* fc1T = (unsigned short*)(ws + 8 * MB);
  unsigned short* fc2T = (unsigned short*)(ws + 16 * MB);
  unsigned short* xn = (unsigned short*)(ws + 24 * MB);
  unsigned short* qkv = (unsigned short*)(ws + 32 * MB);
  unsigned short* attnb = (unsigned short*)(ws + 56 * MB);
  float* x1 = (float*)(ws + 64 * MB);
  unsigned short* x2n = (unsigned short*)(ws + 80 * MB);
  unsigned short* hb = (unsigned short*)(ws + 88 * MB);
  float* posT = (float*)(ws + 120 * MB);

  transpose_w<<<dim3(16, 16), 256, 0, stream>>>(q_w, qkvT, 1024, 1024);
  transpose_w<<<dim3(16, 32), 256, 0, stream>>>(
      kv_w, qkvT + (size_t)1024 * 1024, 1024, 2048);
  transpose_w<<<dim3(16, 16), 256, 0, stream>>>(proj_w, projT, 1024, 1024);
  transpose_w<<<dim3(16, 64), 256, 0, stream>>>(fc1_w, fc1T, 1024, 4096);
  transpose_w<<<dim3(64, 16), 256, 0, stream>>>(fc2_w, fc2T, 4096, 1024);

  ln_kernel<<<4096, 256, 0, stream>>>(x, n1g, n1b, xn);
  pos_mlp<<<993, 256, 0, stream>>>(pp_w, pp_b, ln1g, ln1b, lin1w, lin1b, ln2g,
                                   ln2b, lin2w, lin2b, ln3g, ln3b, lin3w,
                                   lin3b, posT);

  // qkv: 64x128 tiles -> 1536 blocks (72KB LDS: 2/CU)
  gemm_bt<64, 128, false, false, false, true, false>
      <<<dim3(64, 24), 256, 0, stream>>>(xn, qkvT, nullptr, nullptr, qkv,
                                         nullptr, 4096, 3072, 1024);

  attn_kernel<<<512, 256, 0, stream>>>(qkv, posT, attnb);

  // proj: 64x64 tiles -> 1024 blocks (48KB LDS: 3/CU)
  gemm_bt<64, 64, true, false, true, false, true>
      <<<dim3(64, 16), 256, 0, stream>>>(attnb, projT, proj_b, x, nullptr, x1,
                                         4096, 1024, 1024);

  ln_kernel<<<4096, 256, 0, stream>>>(x1, n2g, n2b, x2n);

  // fc1: 64x128 tiles -> 2048 blocks
  gemm_bt<64, 128, true, true, false, true, false>
      <<<dim3(64, 32), 256, 0, stream>>>(x2n, fc1T, fc1_b, nullptr, hb,
                                         nullptr, 4096, 4096, 1024);

  // fc2: 64x64 tiles -> 1024 blocks
  gemm_bt<64, 64, true, false, true, false, true>
      <<<dim3(64, 16), 256, 0, stream>>>(hb, fc2T, fc2_b, x1, nullptr, out,
                                         4096, 1024, 4096);

  (void)in_sizes; (void)n_in; (void)out_size; (void)ws_size;
}

// Round 8
// 239.733 us; speedup vs baseline: 1.3126x; 1.3126x over previous
//
#include <hip/hip_runtime.h>
#include <cstdint>
#include <cstddef>

typedef __attribute__((ext_vector_type(8))) __bf16 bf16x8;
typedef __attribute__((ext_vector_type(8))) unsigned short us8;
typedef __attribute__((ext_vector_type(4))) unsigned short us4;
typedef __attribute__((ext_vector_type(4))) float f32x4;
typedef __attribute__((ext_vector_type(16))) float f32x16;

#define DEVI static __device__ __forceinline__

DEVI unsigned short f2bf(float f) {
  union { float f; unsigned u; } v; v.f = f;
  unsigned r = v.u + 0x7fffu + ((v.u >> 16) & 1u);
  return (unsigned short)(r >> 16);
}

DEVI f32x4 mfma16(us8 a, us8 b, f32x4 c) {
  return __builtin_amdgcn_mfma_f32_16x16x32_bf16(
      __builtin_bit_cast(bf16x8, a), __builtin_bit_cast(bf16x8, b), c, 0, 0, 0);
}

DEVI f32x16 mfma32(us8 a, us8 b, f32x16 c) {
  return __builtin_amdgcn_mfma_f32_32x32x16_bf16(
      __builtin_bit_cast(bf16x8, a), __builtin_bit_cast(bf16x8, b), c, 0, 0, 0);
}

DEVI f32x4 fzero4() { f32x4 v = {0.f, 0.f, 0.f, 0.f}; return v; }

// tanh-form GELU: ~9 VALU ops vs erff's ~20+. |err| < 3e-3 abs.
DEVI float gelu_f(float v) {
  float z = 0.7978845608f * v * (1.f + 0.044715f * v * v);
  float e = __expf(2.f * z);
  float r = 1.f / (e + 1.f);
  return v * (1.f - r);
}

DEVI unsigned pkbf(float lo, float hi) {
  unsigned r;
  asm("v_cvt_pk_bf16_f32 %0, %1, %2" : "=v"(r) : "v"(lo), "v"(hi));
  return r;
}

DEVI void pswap(unsigned& x, unsigned& y) {
  asm volatile("v_permlane32_swap_b32 %0, %1" : "+v"(x), "+v"(y));
}

// global -> LDS direct copy, 16 B per lane.
DEVI void gload16(const unsigned short* g, unsigned short* l) {
  __builtin_amdgcn_global_load_lds(
      (const __attribute__((address_space(1))) unsigned int*)g,
      (__attribute__((address_space(3))) unsigned int*)l, 16, 0, 0);
}

// ---------------------------------------------------------------------------
// Weight transpose + fp32->bf16 cast: w[K][N] -> wt[N][K]
// ---------------------------------------------------------------------------
__global__ __launch_bounds__(256)
void transpose_w(const float* __restrict__ w, unsigned short* __restrict__ wt,
                 int K, int N) {
  __shared__ unsigned short tile[64][65];
  const int t = threadIdx.x;
  const int kb = blockIdx.x * 64, nb = blockIdx.y * 64;
#pragma unroll
  for (int i = 0; i < 4; ++i) {
    int r = i * 16 + (t >> 4);
    int c = (t & 15) * 4;
    float4 v = *(const float4*)(w + (size_t)(kb + r) * N + nb + c);
    tile[r][c + 0] = f2bf(v.x);
    tile[r][c + 1] = f2bf(v.y);
    tile[r][c + 2] = f2bf(v.z);
    tile[r][c + 3] = f2bf(v.w);
  }
  __syncthreads();
#pragma unroll
  for (int i = 0; i < 4; ++i) {
    int n = i * 16 + (t >> 4);
    int k = (t & 15) * 4;
    us4 o;
    o[0] = tile[k + 0][n];
    o[1] = tile[k + 1][n];
    o[2] = tile[k + 2][n];
    o[3] = tile[k + 3][n];
    *(us4*)(wt + (size_t)(nb + n) * K + kb + k) = o;
  }
}

// ---------------------------------------------------------------------------
// LayerNorm over C=1024, fp32 in -> bf16 out.
// ---------------------------------------------------------------------------
__global__ __launch_bounds__(256)
void ln_kernel(const float* __restrict__ x, const float* __restrict__ g,
               const float* __restrict__ b, unsigned short* __restrict__ o) {
  const int row = blockIdx.x;
  const int tid = threadIdx.x;
  const float* xr = x + (size_t)row * 1024;
  float4 v = *(const float4*)(xr + tid * 4);
  float s = v.x + v.y + v.z + v.w;
  float sq = v.x * v.x + v.y * v.y + v.z * v.z + v.w * v.w;
#pragma unroll
  for (int m = 1; m < 64; m <<= 1) {
    s += __shfl_xor(s, m, 64);
    sq += __shfl_xor(sq, m, 64);
  }
  __shared__ float ss[4], ssq[4];
  const int wid = tid >> 6, lane = tid & 63;
  if (lane == 0) { ss[wid] = s; ssq[wid] = sq; }
  __syncthreads();
  s = ss[0] + ss[1] + ss[2] + ss[3];
  sq = ssq[0] + ssq[1] + ssq[2] + ssq[3];
  const float mu = s * (1.f / 1024.f);
  const float var = sq * (1.f / 1024.f) - mu * mu;
  const float rstd = rsqrtf(var + 1e-5f);
  const int c = tid * 4;
  float4 gv = *(const float4*)(g + c);
  float4 bv = *(const float4*)(b + c);
  us4 ov;
  ov[0] = f2bf((v.x - mu) * rstd * gv.x + bv.x);
  ov[1] = f2bf((v.y - mu) * rstd * gv.y + bv.y);
  ov[2] = f2bf((v.z - mu) * rstd * gv.z + bv.z);
  ov[3] = f2bf((v.w - mu) * rstd * gv.w + bv.w);
  *(us4*)(o + (size_t)row * 1024 + c) = ov;
}

// ---------------------------------------------------------------------------
// DynamicPosBias MLP -> posT[16][3969] (f32). One wave per row.
// ---------------------------------------------------------------------------
DEVI float pos_layer(float p, const float* __restrict__ g,
                     const float* __restrict__ be, const float* __restrict__ w,
                     const float* __restrict__ bb, int lane) {
  float s = p, sq = p * p;
#pragma unroll
  for (int m = 1; m < 64; m <<= 1) {
    s += __shfl_xor(s, m, 64);
    sq += __shfl_xor(sq, m, 64);
  }
  float mu = s * (1.f / 64.f);
  float var = sq * (1.f / 64.f) - mu * mu;
  float rstd = rsqrtf(var + 1e-5f);
  float y = fmaxf((p - mu) * rstd * g[lane] + be[lane], 0.f);
  float o = bb[lane];
  for (int k = 0; k < 64; ++k) {
    float yk = __shfl(y, k, 64);
    o += yk * w[k * 64 + lane];
  }
  return o;
}

__global__ __launch_bounds__(256)
void pos_mlp(const float* __restrict__ pp_w, const float* __restrict__ pp_b,
             const float* __restrict__ g1, const float* __restrict__ b1,
             const float* __restrict__ w1, const float* __restrict__ bb1,
             const float* __restrict__ g2, const float* __restrict__ b2,
             const float* __restrict__ w2, const float* __restrict__ bb2,
             const float* __restrict__ g3, const float* __restrict__ b3,
             const float* __restrict__ w3, const float* __restrict__ bb3,
             float* __restrict__ posT) {
  const int wid = threadIdx.x >> 6, lane = threadIdx.x & 63;
  const int row = blockIdx.x * 4 + wid;
  if (row >= 3969) return;
  const float bh = (float)(row / 63) - 31.f;
  const float bw = (float)(row % 63) - 31.f;
  float p = bh * pp_w[lane] + bw * pp_w[64 + lane] + pp_b[lane];
  p = pos_layer(p, g1, b1, w1, bb1, lane);
  p = pos_layer(p, g2, b2, w2, bb2, lane);
  float s = p, sq = p * p;
#pragma unroll
  for (int m = 1; m < 64; m <<= 1) {
    s += __shfl_xor(s, m, 64);
    sq += __shfl_xor(sq, m, 64);
  }
  float mu = s * (1.f / 64.f);
  float var = sq * (1.f / 64.f) - mu * mu;
  float rstd = rsqrtf(var + 1e-5f);
  float y = fmaxf((p - mu) * rstd * g3[lane] + b3[lane], 0.f);
  float o = 0.f;
  for (int k = 0; k < 64; ++k) {
    float yk = __shfl(y, k, 64);
    o += yk * w3[k * 16 + (lane & 15)];
  }
  if (lane < 16) posT[(size_t)lane * 3969 + row] = o + bb3[lane];
}

// ---------------------------------------------------------------------------
// GEMM, BK=128, single-buffered 2-barrier loop: halves drain events vs BK=64
// and doubles MFMA per barrier. LDS rows are 256B; T2 swizzle adapted:
// LDS chunk c of row r holds global chunk c ^ ((r&7)<<1) (involution), applied
// on the global source (gload_lds dest stays linear) and on ds_read.
// Tile BM x BN, 4 waves (2x2 of (BM/2)x(BN/2)).
// ---------------------------------------------------------------------------
template <int BM, int BN, bool HAS_BIAS, bool GELU_, bool HAS_RES,
          bool OUT_BF16, bool OUT_F32>
__global__ __launch_bounds__(256)
void gemm_bt(const unsigned short* __restrict__ A,
             const unsigned short* __restrict__ Bt,
             const float* __restrict__ bias, const float* __restrict__ res,
             unsigned short* __restrict__ outb, float* __restrict__ outf,
             int M, int N, int K) {
  constexpr int MT = BM / 32;
  constexpr int NT = BN / 32;
  __shared__ unsigned short As[BM * 128];
  __shared__ unsigned short Bs[BN * 128];
  const int tid = threadIdx.x;
  const int lane = tid & 63;
  const int wid = tid >> 6;
  const int lr = lane & 15, lg = lane >> 4;
  const int wr = wid >> 1, wc = wid & 1;
  const int brow = blockIdx.x, bcol = blockIdx.y;

  f32x4 acc[MT][NT];
#pragma unroll
  for (int mt = 0; mt < MT; ++mt)
#pragma unroll
    for (int nt = 0; nt < NT; ++nt) acc[mt][nt] = fzero4();

  // staging: per gload16 call a wave writes 4 rows x 256B (linear dest).
  // lane -> row wid*4 + (lane>>4), chunk lane&15. Source chunk pre-swizzled.
  const int sr = wid * 4 + (lane >> 4);            // row within 16-row group
  const int sc = ((lane & 15) ^ ((sr & 7) << 1)) * 8;  // swizzled elem offset
  const unsigned short* Ag = A + (size_t)(brow * BM + sr) * K + sc;
  const unsigned short* Bg = Bt + (size_t)(bcol * BN + sr) * K + sc;

  const int nkb = K >> 7;
  for (int kb = 0; kb < nkb; ++kb) {
    __syncthreads();  // previous iteration's LDS readers done
#pragma unroll
    for (int q = 0; q < BM / 16; ++q)
      gload16(Ag + (size_t)(q * 16) * K + kb * 128,
              As + (q * 16 + wid * 4) * 128);
#pragma unroll
    for (int q = 0; q < BN / 16; ++q)
      gload16(Bg + (size_t)(q * 16) * K + kb * 128,
              Bs + (q * 16 + wid * 4) * 128);
    __syncthreads();  // drain vmcnt(0) before compute
#pragma unroll
    for (int ks = 0; ks < 4; ++ks) {
      us8 af[MT], bfr[NT];
#pragma unroll
      for (int mt = 0; mt < MT; ++mt) {
        const int r = wr * (BM / 2) + mt * 16 + lr;
        const int ck = (ks * 4 + lg) ^ ((r & 7) << 1);
        af[mt] = *(const us8*)((const char*)As + r * 256 + ck * 16);
      }
#pragma unroll
      for (int nt = 0; nt < NT; ++nt) {
        const int r = wc * (BN / 2) + nt * 16 + lr;
        const int ck = (ks * 4 + lg) ^ ((r & 7) << 1);
        bfr[nt] = *(const us8*)((const char*)Bs + r * 256 + ck * 16);
      }
      __builtin_amdgcn_s_setprio(1);
#pragma unroll
      for (int mt = 0; mt < MT; ++mt)
#pragma unroll
        for (int nt = 0; nt < NT; ++nt)
          acc[mt][nt] = mfma16(af[mt], bfr[nt], acc[mt][nt]);
      __builtin_amdgcn_s_setprio(0);
    }
  }

#pragma unroll
  for (int mt = 0; mt < MT; ++mt) {
    const int row = brow * BM + wr * (BM / 2) + mt * 16 + 4 * lg;
#pragma unroll
    for (int nt = 0; nt < NT; ++nt) {
      const int col = bcol * BN + wc * (BN / 2) + nt * 16 + lr;
      float bsv = 0.f;
      if constexpr (HAS_BIAS) bsv = bias[col];
#pragma unroll
      for (int i = 0; i < 4; ++i) {
        float v = acc[mt][nt][i] + bsv;
        if constexpr (GELU_) v = gelu_f(v);
        if constexpr (HAS_RES) v += res[(size_t)(row + i) * N + col];
        if constexpr (OUT_F32) outf[(size_t)(row + i) * N + col] = v;
        if constexpr (OUT_BF16) outb[(size_t)(row + i) * N + col] = f2bf(v);
      }
    }
  }
}

// ---------------------------------------------------------------------------
// Flash attention, swapped-QK^T 32x32 structure (T12) + dynamic pos bias.
// ---------------------------------------------------------------------------
__global__ __launch_bounds__(256)
void attn_kernel(const unsigned short* __restrict__ qkv,
                 const float* __restrict__ posT,
                 unsigned short* __restrict__ attnb) {
  __shared__ unsigned short Ks[64 * 64];  // [k][d], XOR-swizzled rows
  __shared__ unsigned short Vt[64 * 64];  // [d][k], XOR-swizzled rows

  const int tid = threadIdx.x;
  const int wid = tid >> 6;
  const int lane = tid & 63;
  const int ql = lane & 31;
  const int hi = lane >> 5;

  const int p = blockIdx.x;
  const int orig = (p & 7) * 64 + (p >> 3);
  const int b = orig >> 7;
  const int h = (orig >> 3) & 15;
  const int qt = orig & 7;

  const int LDQ = 3072;
  const int qg = qt * 128 + wid * 32 + ql;

  us8 qf[4];
  const unsigned short* qptr =
      qkv + (size_t)(b * 1024 + qg) * LDQ + h * 64 + 8 * hi;
#pragma unroll
  for (int db = 0; db < 4; ++db) qf[db] = *(const us8*)(qptr + db * 16);

  const float* pb = posT + (size_t)h * 3969;
  const int rb_q = ((qg >> 5) + 31) * 63 + (qg & 31) + 31 - 4 * hi;

  f32x16 oacc[2];
#pragma unroll
  for (int r = 0; r < 16; ++r) { oacc[0][r] = 0.f; oacc[1][r] = 0.f; }
  float mreg = -1e30f, lsum = 0.f;

  const int ksr = tid >> 2;
  const int ksc = (tid & 3) * 16;
  const int vk0 = (tid >> 4) * 4;
  const int vd0 = (tid & 15) * 4;

  const unsigned short* kbase = qkv + (size_t)(b * 1024) * LDQ + 1024 + h * 64;
  const unsigned short* vbase = qkv + (size_t)(b * 1024) * LDQ + 2048 + h * 64;

  us8 pk0 = *(const us8*)(kbase + (size_t)ksr * LDQ + ksc);
  us8 pk1 = *(const us8*)(kbase + (size_t)ksr * LDQ + ksc + 8);
  us4 pvv[4];
#pragma unroll
  for (int j = 0; j < 4; ++j)
    pvv[j] = *(const us4*)(vbase + (size_t)(vk0 + j) * LDQ + vd0);

  for (int kt = 0; kt < 16; ++kt) {
    __syncthreads();
    {
      char* ksb = (char*)Ks;
      const int swr = (ksr & 7) << 4;
      *(us8*)(ksb + ksr * 128 + ((ksc * 2) ^ swr)) = pk0;
      *(us8*)(ksb + ksr * 128 + (((ksc + 8) * 2) ^ swr)) = pk1;
      char* vtb = (char*)Vt;
#pragma unroll
      for (int u = 0; u < 4; ++u) {
        us4 w;
        w[0] = pvv[0][u]; w[1] = pvv[1][u]; w[2] = pvv[2][u]; w[3] = pvv[3][u];
        const int d = vd0 + u;
        *(us4*)(vtb + d * 128 + ((vk0 * 2) ^ ((d & 7) << 4))) = w;
      }
    }
    __syncthreads();

    if (kt < 15) {
      const unsigned short* kb2 = kbase + (size_t)((kt + 1) * 64) * LDQ;
      const unsigned short* vb2 = vbase + (size_t)((kt + 1) * 64) * LDQ;
      pk0 = *(const us8*)(kb2 + (size_t)ksr * LDQ + ksc);
      pk1 = *(const us8*)(kb2 + (size_t)ksr * LDQ + ksc + 8);
#pragma unroll
      for (int j = 0; j < 4; ++j)
        pvv[j] = *(const us4*)(vb2 + (size_t)(vk0 + j) * LDQ + vd0);
    }

    f32x16 st0, st1;
#pragma unroll
    for (int r = 0; r < 16; ++r) { st0[r] = 0.f; st1[r] = 0.f; }
    const char* ksb = (const char*)Ks;
    const int kswz = (ql & 7) << 4;
    __builtin_amdgcn_s_setprio(1);
#pragma unroll
    for (int db = 0; db < 4; ++db) {
      const int coff = (db * 32 + 16 * hi) ^ kswz;
      us8 kf0 = *(const us8*)(ksb + ql * 128 + coff);
      us8 kf1 = *(const us8*)(ksb + (32 + ql) * 128 + coff);
      st0 = mfma32(kf0, qf[db], st0);
      st1 = mfma32(kf1, qf[db], st1);
    }
    __builtin_amdgcn_s_setprio(0);

    float sv0[16], sv1[16];
    const float* pb0 = pb + (rb_q - 63 * (2 * kt));
    const float* pb1 = pb0 - 63;
    float mm[16];
#pragma unroll
    for (int r = 0; r < 16; ++r) {
      const int roff = (r & 3) + 8 * (r >> 2);
      float a = st0[r] * 0.125f + pb0[-roff];
      float c = st1[r] * 0.125f + pb1[-roff];
      sv0[r] = a;
      sv1[r] = c;
      mm[r] = fmaxf(a, c);
    }
#pragma unroll
    for (int w = 8; w >= 1; w >>= 1)
#pragma unroll
      for (int r = 0; r < w; ++r) mm[r] = fmaxf(mm[r], mm[r + w]);
    float mx = fmaxf(mreg, mm[0]);
    mx = fmaxf(mx, __shfl_xor(mx, 32, 64));
    const float f = __expf(mreg - mx);
    mreg = mx;

    float ts[16];
#pragma unroll
    for (int r = 0; r < 16; ++r) {
      float e0 = __expf(sv0[r] - mx);
      float e1 = __expf(sv1[r] - mx);
      sv0[r] = e0;
      sv1[r] = e1;
      ts[r] = e0 + e1;
    }
#pragma unroll
    for (int w = 8; w >= 1; w >>= 1)
#pragma unroll
      for (int r = 0; r < w; ++r) ts[r] += ts[r + w];
    lsum = lsum * f + ts[0];
#pragma unroll
    for (int r = 0; r < 16; ++r) { oacc[0][r] *= f; oacc[1][r] *= f; }

    const char* vtb = (const char*)Vt;
    auto pvfrag = [&](const float* sv, int kb) {
      const int B0 = (kb & 1) * 8;
      unsigned a0 = pkbf(sv[B0 + 0], sv[B0 + 1]);
      unsigned a1 = pkbf(sv[B0 + 2], sv[B0 + 3]);
      unsigned b0 = pkbf(sv[B0 + 4], sv[B0 + 5]);
      unsigned b1 = pkbf(sv[B0 + 6], sv[B0 + 7]);
      pswap(a0, b0);
      pswap(a1, b1);
      union { us8 s; unsigned u[4]; } fu;
      fu.u[0] = a0; fu.u[1] = a1; fu.u[2] = b0; fu.u[3] = b1;
      const int coff = (kb * 32 + 16 * hi) ^ kswz;
      us8 vf0 = *(const us8*)(vtb + ql * 128 + coff);
      us8 vf1 = *(const us8*)(vtb + (32 + ql) * 128 + coff);
      __builtin_amdgcn_s_setprio(1);
      oacc[0] = mfma32(vf0, fu.s, oacc[0]);
      oacc[1] = mfma32(vf1, fu.s, oacc[1]);
      __builtin_amdgcn_s_setprio(0);
    };
    pvfrag(sv0, 0);
    pvfrag(sv0, 1);
    pvfrag(sv1, 2);
    pvfrag(sv1, 3);
  }

  lsum += __shfl_xor(lsum, 32, 64);
  const float inv = 1.f / lsum;
  unsigned short* orow = attnb + (size_t)(b * 1024 + qg) * 1024 + h * 64;
#pragma unroll
  for (int dm = 0; dm < 2; ++dm)
#pragma unroll
    for (int r = 0; r < 16; ++r) {
      const int d = dm * 32 + (r & 3) + 8 * (r >> 2) + 4 * hi;
      orow[d] = f2bf(oacc[dm][r] * inv);
    }
}

// ---------------------------------------------------------------------------
// Launcher
// ---------------------------------------------------------------------------
extern "C" void kernel_launch(void* const* d_in, const int* in_sizes, int n_in,
                              void* d_out, int out_size, void* d_ws,
                              size_t ws_size, hipStream_t stream) {
  const float* x = (const float*)d_in[0];
  const float* n1g = (const float*)d_in[1];
  const float* n1b = (const float*)d_in[2];
  const float* q_w = (const float*)d_in[3];
  const float* kv_w = (const float*)d_in[4];
  const float* proj_w = (const float*)d_in[5];
  const float* proj_b = (const float*)d_in[6];
  const float* pp_w = (const float*)d_in[7];
  const float* pp_b = (const float*)d_in[8];
  const float* ln1g = (const float*)d_in[9];
  const float* ln1b = (const float*)d_in[10];
  const float* lin1w = (const float*)d_in[11];
  const float* lin1b = (const float*)d_in[12];
  const float* ln2g = (const float*)d_in[13];
  const float* ln2b = (const float*)d_in[14];
  const float* lin2w = (const float*)d_in[15];
  const float* lin2b = (const float*)d_in[16];
  const float* ln3g = (const float*)d_in[17];
  const float* ln3b = (const float*)d_in[18];
  const float* lin3w = (const float*)d_in[19];
  const float* lin3b = (const float*)d_in[20];
  const float* n2g = (const float*)d_in[21];
  const float* n2b = (const float*)d_in[22];
  const float* fc1_w = (const float*)d_in[23];
  const float* fc1_b = (const float*)d_in[24];
  const float* fc2_w = (const float*)d_in[25];
  const float* fc2_b = (const float*)d_in[26];
  float* out = (float*)d_out;

  char* ws = (char*)d_ws;
  const size_t MB = 1024ull * 1024ull;
  unsigned short* qkvT = (unsigned short*)(ws + 0 * MB);
  unsigned short* projT = (unsigned short*)(ws + 6 * MB);
  unsigned short* fc1T = (unsigned short*)(ws + 8 * MB);
  unsigned short* fc2T = (unsigned short*)(ws + 16 * MB);
  unsigned short* xn = (unsigned short*)(ws + 24 * MB);
  unsigned short* qkv = (unsigned short*)(ws + 32 * MB);
  unsigned short* attnb = (unsigned short*)(ws + 56 * MB);
  float* x1 = (float*)(ws + 64 * MB);
  unsigned short* x2n = (unsigned short*)(ws + 80 * MB);
  unsigned short* hb = (unsigned short*)(ws + 88 * MB);
  float* posT = (float*)(ws + 120 * MB);

  transpose_w<<<dim3(16, 16), 256, 0, stream>>>(q_w, qkvT, 1024, 1024);
  transpose_w<<<dim3(16, 32), 256, 0, stream>>>(
      kv_w, qkvT + (size_t)1024 * 1024, 1024, 2048);
  transpose_w<<<dim3(16, 16), 256, 0, stream>>>(proj_w, projT, 1024, 1024);
  transpose_w<<<dim3(16, 64), 256, 0, stream>>>(fc1_w, fc1T, 1024, 4096);
  transpose_w<<<dim3(64, 16), 256, 0, stream>>>(fc2_w, fc2T, 4096, 1024);

  ln_kernel<<<4096, 256, 0, stream>>>(x, n1g, n1b, xn);
  pos_mlp<<<993, 256, 0, stream>>>(pp_w, pp_b, ln1g, ln1b, lin1w, lin1b, ln2g,
                                   ln2b, lin2w, lin2b, ln3g, ln3b, lin3w,
                                   lin3b, posT);

  // qkv: 128x128, BK=128 -> 768 blocks (64KB LDS: 2/CU)
  gemm_bt<128, 128, false, false, false, true, false>
      <<<dim3(32, 24), 256, 0, stream>>>(xn, qkvT, nullptr, nullptr, qkv,
                                         nullptr, 4096, 3072, 1024);

  attn_kernel<<<512, 256, 0, stream>>>(qkv, posT, attnb);

  // proj: 64x128, BK=128 -> 512 blocks (48KB LDS: 2-3/CU)
  gemm_bt<64, 128, true, false, true, false, true>
      <<<dim3(64, 8), 256, 0, stream>>>(attnb, projT, proj_b, x, nullptr, x1,
                                        4096, 1024, 1024);

  ln_kernel<<<4096, 256, 0, stream>>>(x1, n2g, n2b, x2n);

  // fc1: 128x128, BK=128 -> 1024 blocks (64KB LDS: 2/CU)
  gemm_bt<128, 128, true, true, false, true, false>
      <<<dim3(32, 32), 256, 0, stream>>>(x2n, fc1T, fc1_b, nullptr, hb,
                                         nullptr, 4096, 4096, 1024);

  // fc2: 64x128, BK=128 -> 512 blocks (48KB LDS: 2-3/CU)
  gemm_bt<64, 128, true, false, true, false, true>
      <<<dim3(64, 8), 256, 0, stream>>>(hb, fc2T, fc2_b, x1, nullptr, out,
                                        4096, 1024, 4096);

  (void)in_sizes; (void)n_in; (void)out_size; (void)ws_size;
}

// Round 9
// 223.265 us; speedup vs baseline: 1.4094x; 1.0738x over previous
//
#include <hip/hip_runtime.h>
#include <cstdint>
#include <cstddef>

typedef __attribute__((ext_vector_type(8))) __bf16 bf16x8;
typedef __attribute__((ext_vector_type(8))) unsigned short us8;
typedef __attribute__((ext_vector_type(4))) unsigned short us4;
typedef __attribute__((ext_vector_type(4))) float f32x4;
typedef __attribute__((ext_vector_type(16))) float f32x16;

#define DEVI static __device__ __forceinline__

DEVI unsigned short f2bf(float f) {
  union { float f; unsigned u; } v; v.f = f;
  unsigned r = v.u + 0x7fffu + ((v.u >> 16) & 1u);
  return (unsigned short)(r >> 16);
}

DEVI f32x4 mfma16(us8 a, us8 b, f32x4 c) {
  return __builtin_amdgcn_mfma_f32_16x16x32_bf16(
      __builtin_bit_cast(bf16x8, a), __builtin_bit_cast(bf16x8, b), c, 0, 0, 0);
}

DEVI f32x16 mfma32(us8 a, us8 b, f32x16 c) {
  return __builtin_amdgcn_mfma_f32_32x32x16_bf16(
      __builtin_bit_cast(bf16x8, a), __builtin_bit_cast(bf16x8, b), c, 0, 0, 0);
}

DEVI f32x4 fzero4() { f32x4 v = {0.f, 0.f, 0.f, 0.f}; return v; }

// tanh-form GELU: ~9 VALU ops vs erff's ~20+. |err| < 3e-3 abs.
DEVI float gelu_f(float v) {
  float z = 0.7978845608f * v * (1.f + 0.044715f * v * v);
  float e = __expf(2.f * z);
  float r = 1.f / (e + 1.f);
  return v * (1.f - r);
}

DEVI unsigned pkbf(float lo, float hi) {
  unsigned r;
  asm("v_cvt_pk_bf16_f32 %0, %1, %2" : "=v"(r) : "v"(lo), "v"(hi));
  return r;
}

DEVI void pswap(unsigned& x, unsigned& y) {
  asm volatile("v_permlane32_swap_b32 %0, %1" : "+v"(x), "+v"(y));
}

// global -> LDS direct copy, 16 B per lane.
DEVI void gload16(const unsigned short* g, unsigned short* l) {
  __builtin_amdgcn_global_load_lds(
      (const __attribute__((address_space(1))) unsigned int*)g,
      (__attribute__((address_space(3))) unsigned int*)l, 16, 0, 0);
}

// ---------------------------------------------------------------------------
// Merged prep kernel: LN1 (4096 blocks) + pos_mlp (993) + 5 weight transposes
// (3072). One launch replaces 7. All branches are block-uniform.
// ---------------------------------------------------------------------------
DEVI void transpose_body(const float* __restrict__ w,
                         unsigned short* __restrict__ wt, int K, int N,
                         int kbi, int nbi, unsigned short (*tile)[65]) {
  const int t = threadIdx.x;
  const int kb = kbi * 64, nb = nbi * 64;
#pragma unroll
  for (int i = 0; i < 4; ++i) {
    int r = i * 16 + (t >> 4);
    int c = (t & 15) * 4;
    float4 v = *(const float4*)(w + (size_t)(kb + r) * N + nb + c);
    tile[r][c + 0] = f2bf(v.x);
    tile[r][c + 1] = f2bf(v.y);
    tile[r][c + 2] = f2bf(v.z);
    tile[r][c + 3] = f2bf(v.w);
  }
  __syncthreads();
#pragma unroll
  for (int i = 0; i < 4; ++i) {
    int n = i * 16 + (t >> 4);
    int k = (t & 15) * 4;
    us4 o;
    o[0] = tile[k + 0][n];
    o[1] = tile[k + 1][n];
    o[2] = tile[k + 2][n];
    o[3] = tile[k + 3][n];
    *(us4*)(wt + (size_t)(nb + n) * K + kb + k) = o;
  }
}

DEVI float pos_layer(float p, const float* __restrict__ g,
                     const float* __restrict__ be, const float* __restrict__ w,
                     const float* __restrict__ bb, int lane) {
  float s = p, sq = p * p;
#pragma unroll
  for (int m = 1; m < 64; m <<= 1) {
    s += __shfl_xor(s, m, 64);
    sq += __shfl_xor(sq, m, 64);
  }
  float mu = s * (1.f / 64.f);
  float var = sq * (1.f / 64.f) - mu * mu;
  float rstd = rsqrtf(var + 1e-5f);
  float y = fmaxf((p - mu) * rstd * g[lane] + be[lane], 0.f);
  float o = bb[lane];
  for (int k = 0; k < 64; ++k) {
    float yk = __shfl(y, k, 64);
    o += yk * w[k * 64 + lane];
  }
  return o;
}

__global__ __launch_bounds__(256)
void prep_kernel(const float* __restrict__ x, const float* __restrict__ n1g,
                 const float* __restrict__ n1b, unsigned short* __restrict__ xn,
                 const float* __restrict__ q_w, const float* __restrict__ kv_w,
                 const float* __restrict__ proj_w,
                 const float* __restrict__ fc1_w,
                 const float* __restrict__ fc2_w,
                 unsigned short* __restrict__ qkvT,
                 unsigned short* __restrict__ projT,
                 unsigned short* __restrict__ fc1T,
                 unsigned short* __restrict__ fc2T,
                 const float* __restrict__ pp_w, const float* __restrict__ pp_b,
                 const float* __restrict__ g1, const float* __restrict__ b1,
                 const float* __restrict__ w1, const float* __restrict__ bb1,
                 const float* __restrict__ g2, const float* __restrict__ b2,
                 const float* __restrict__ w2, const float* __restrict__ bb2,
                 const float* __restrict__ g3, const float* __restrict__ b3,
                 const float* __restrict__ w3, const float* __restrict__ bb3,
                 float* __restrict__ posT) {
  __shared__ unsigned short tile[64][65];
  __shared__ float ss[4], ssq[4];
  const int blk = blockIdx.x;
  const int tid = threadIdx.x;

  if (blk < 4096) {  // -------- LN1 --------
    const int row = blk;
    const float* xr = x + (size_t)row * 1024;
    float4 v = *(const float4*)(xr + tid * 4);
    float s = v.x + v.y + v.z + v.w;
    float sq = v.x * v.x + v.y * v.y + v.z * v.z + v.w * v.w;
#pragma unroll
    for (int m = 1; m < 64; m <<= 1) {
      s += __shfl_xor(s, m, 64);
      sq += __shfl_xor(sq, m, 64);
    }
    const int wid = tid >> 6, lane = tid & 63;
    if (lane == 0) { ss[wid] = s; ssq[wid] = sq; }
    __syncthreads();
    s = ss[0] + ss[1] + ss[2] + ss[3];
    sq = ssq[0] + ssq[1] + ssq[2] + ssq[3];
    const float mu = s * (1.f / 1024.f);
    const float var = sq * (1.f / 1024.f) - mu * mu;
    const float rstd = rsqrtf(var + 1e-5f);
    const int c = tid * 4;
    float4 gv = *(const float4*)(n1g + c);
    float4 bv = *(const float4*)(n1b + c);
    us4 ov;
    ov[0] = f2bf((v.x - mu) * rstd * gv.x + bv.x);
    ov[1] = f2bf((v.y - mu) * rstd * gv.y + bv.y);
    ov[2] = f2bf((v.z - mu) * rstd * gv.z + bv.z);
    ov[3] = f2bf((v.w - mu) * rstd * gv.w + bv.w);
    *(us4*)(xn + (size_t)row * 1024 + c) = ov;
  } else if (blk < 5089) {  // -------- pos MLP --------
    const int wid = tid >> 6, lane = tid & 63;
    const int row = (blk - 4096) * 4 + wid;
    if (row >= 3969) return;
    const float bh = (float)(row / 63) - 31.f;
    const float bw = (float)(row % 63) - 31.f;
    float p = bh * pp_w[lane] + bw * pp_w[64 + lane] + pp_b[lane];
    p = pos_layer(p, g1, b1, w1, bb1, lane);
    p = pos_layer(p, g2, b2, w2, bb2, lane);
    float s = p, sq = p * p;
#pragma unroll
    for (int m = 1; m < 64; m <<= 1) {
      s += __shfl_xor(s, m, 64);
      sq += __shfl_xor(sq, m, 64);
    }
    float mu = s * (1.f / 64.f);
    float var = sq * (1.f / 64.f) - mu * mu;
    float rstd = rsqrtf(var + 1e-5f);
    float y = fmaxf((p - mu) * rstd * g3[lane] + b3[lane], 0.f);
    float o = 0.f;
    for (int k = 0; k < 64; ++k) {
      float yk = __shfl(y, k, 64);
      o += yk * w3[k * 16 + (lane & 15)];
    }
    if (lane < 16) posT[(size_t)lane * 3969 + row] = o + bb3[lane];
  } else if (blk < 5345) {  // q_w: [1024][1024] -> qkvT rows 0..1023
    const int lin = blk - 5089;
    transpose_body(q_w, qkvT, 1024, 1024, lin & 15, lin >> 4, tile);
  } else if (blk < 5857) {  // kv_w: [1024][2048] -> qkvT rows 1024..3071
    const int lin = blk - 5345;
    transpose_body(kv_w, qkvT + (size_t)1024 * 1024, 1024, 2048, lin & 15,
                   lin >> 4, tile);
  } else if (blk < 6113) {  // proj_w
    const int lin = blk - 5857;
    transpose_body(proj_w, projT, 1024, 1024, lin & 15, lin >> 4, tile);
  } else if (blk < 7137) {  // fc1_w: [1024][4096]
    const int lin = blk - 6113;
    transpose_body(fc1_w, fc1T, 1024, 4096, lin & 15, lin >> 4, tile);
  } else {  // fc2_w: [4096][1024]
    const int lin = blk - 7137;
    transpose_body(fc2_w, fc2T, 4096, 1024, lin & 63, lin >> 6, tile);
  }
}

// ---------------------------------------------------------------------------
// LayerNorm over C=1024, fp32 in -> bf16 out (for LN2).
// ---------------------------------------------------------------------------
__global__ __launch_bounds__(256)
void ln_kernel(const float* __restrict__ x, const float* __restrict__ g,
               const float* __restrict__ b, unsigned short* __restrict__ o) {
  const int row = blockIdx.x;
  const int tid = threadIdx.x;
  const float* xr = x + (size_t)row * 1024;
  float4 v = *(const float4*)(xr + tid * 4);
  float s = v.x + v.y + v.z + v.w;
  float sq = v.x * v.x + v.y * v.y + v.z * v.z + v.w * v.w;
#pragma unroll
  for (int m = 1; m < 64; m <<= 1) {
    s += __shfl_xor(s, m, 64);
    sq += __shfl_xor(sq, m, 64);
  }
  __shared__ float ss[4], ssq[4];
  const int wid = tid >> 6, lane = tid & 63;
  if (lane == 0) { ss[wid] = s; ssq[wid] = sq; }
  __syncthreads();
  s = ss[0] + ss[1] + ss[2] + ss[3];
  sq = ssq[0] + ssq[1] + ssq[2] + ssq[3];
  const float mu = s * (1.f / 1024.f);
  const float var = sq * (1.f / 1024.f) - mu * mu;
  const float rstd = rsqrtf(var + 1e-5f);
  const int c = tid * 4;
  float4 gv = *(const float4*)(g + c);
  float4 bv = *(const float4*)(b + c);
  us4 ov;
  ov[0] = f2bf((v.x - mu) * rstd * gv.x + bv.x);
  ov[1] = f2bf((v.y - mu) * rstd * gv.y + bv.y);
  ov[2] = f2bf((v.z - mu) * rstd * gv.z + bv.z);
  ov[3] = f2bf((v.w - mu) * rstd * gv.w + bv.w);
  *(us4*)(o + (size_t)row * 1024 + c) = ov;
}

// ---------------------------------------------------------------------------
// GEMM (round-8 structure): BK=128, single-buffered 2-barrier loop, swizzled.
// ---------------------------------------------------------------------------
template <int BM, int BN, bool HAS_BIAS, bool GELU_, bool HAS_RES,
          bool OUT_BF16, bool OUT_F32>
__global__ __launch_bounds__(256)
void gemm_bt(const unsigned short* __restrict__ A,
             const unsigned short* __restrict__ Bt,
             const float* __restrict__ bias, const float* __restrict__ res,
             unsigned short* __restrict__ outb, float* __restrict__ outf,
             int M, int N, int K) {
  constexpr int MT = BM / 32;
  constexpr int NT = BN / 32;
  __shared__ unsigned short As[BM * 128];
  __shared__ unsigned short Bs[BN * 128];
  const int tid = threadIdx.x;
  const int lane = tid & 63;
  const int wid = tid >> 6;
  const int lr = lane & 15, lg = lane >> 4;
  const int wr = wid >> 1, wc = wid & 1;
  const int brow = blockIdx.x, bcol = blockIdx.y;

  f32x4 acc[MT][NT];
#pragma unroll
  for (int mt = 0; mt < MT; ++mt)
#pragma unroll
    for (int nt = 0; nt < NT; ++nt) acc[mt][nt] = fzero4();

  const int sr = wid * 4 + (lane >> 4);
  const int sc = ((lane & 15) ^ ((sr & 7) << 1)) * 8;
  const unsigned short* Ag = A + (size_t)(brow * BM + sr) * K + sc;
  const unsigned short* Bg = Bt + (size_t)(bcol * BN + sr) * K + sc;

  const int nkb = K >> 7;
  for (int kb = 0; kb < nkb; ++kb) {
    __syncthreads();
#pragma unroll
    for (int q = 0; q < BM / 16; ++q)
      gload16(Ag + (size_t)(q * 16) * K + kb * 128,
              As + (q * 16 + wid * 4) * 128);
#pragma unroll
    for (int q = 0; q < BN / 16; ++q)
      gload16(Bg + (size_t)(q * 16) * K + kb * 128,
              Bs + (q * 16 + wid * 4) * 128);
    __syncthreads();
#pragma unroll
    for (int ks = 0; ks < 4; ++ks) {
      us8 af[MT], bfr[NT];
#pragma unroll
      for (int mt = 0; mt < MT; ++mt) {
        const int r = wr * (BM / 2) + mt * 16 + lr;
        const int ck = (ks * 4 + lg) ^ ((r & 7) << 1);
        af[mt] = *(const us8*)((const char*)As + r * 256 + ck * 16);
      }
#pragma unroll
      for (int nt = 0; nt < NT; ++nt) {
        const int r = wc * (BN / 2) + nt * 16 + lr;
        const int ck = (ks * 4 + lg) ^ ((r & 7) << 1);
        bfr[nt] = *(const us8*)((const char*)Bs + r * 256 + ck * 16);
      }
      __builtin_amdgcn_s_setprio(1);
#pragma unroll
      for (int mt = 0; mt < MT; ++mt)
#pragma unroll
        for (int nt = 0; nt < NT; ++nt)
          acc[mt][nt] = mfma16(af[mt], bfr[nt], acc[mt][nt]);
      __builtin_amdgcn_s_setprio(0);
    }
  }

#pragma unroll
  for (int mt = 0; mt < MT; ++mt) {
    const int row = brow * BM + wr * (BM / 2) + mt * 16 + 4 * lg;
#pragma unroll
    for (int nt = 0; nt < NT; ++nt) {
      const int col = bcol * BN + wc * (BN / 2) + nt * 16 + lr;
      float bsv = 0.f;
      if constexpr (HAS_BIAS) bsv = bias[col];
#pragma unroll
      for (int i = 0; i < 4; ++i) {
        float v = acc[mt][nt][i] + bsv;
        if constexpr (GELU_) v = gelu_f(v);
        if constexpr (HAS_RES) v += res[(size_t)(row + i) * N + col];
        if constexpr (OUT_F32) outf[(size_t)(row + i) * N + col] = v;
        if constexpr (OUT_BF16) outb[(size_t)(row + i) * N + col] = f2bf(v);
      }
    }
  }
}

// ---------------------------------------------------------------------------
// Flash attention, swapped-QK^T 32x32 (T12) + defer-max (T13).
// 2 waves x 32 q-rows = 64 q per block -> grid 1024 (4 blocks/CU), LDS 16KB.
// ---------------------------------------------------------------------------
__global__ __launch_bounds__(128)
void attn_kernel(const unsigned short* __restrict__ qkv,
                 const float* __restrict__ posT,
                 unsigned short* __restrict__ attnb) {
  __shared__ unsigned short Ks[64 * 64];  // [k][d], XOR-swizzled rows
  __shared__ unsigned short Vt[64 * 64];  // [d][k], XOR-swizzled rows

  const int tid = threadIdx.x;
  const int wid = tid >> 6;  // 0..1
  const int lane = tid & 63;
  const int ql = lane & 31;
  const int hi = lane >> 5;

  // XCD swizzle: 1024 blocks, 128 consecutive orig ids per XCD.
  const int p = blockIdx.x;
  const int orig = (p & 7) * 128 + (p >> 3);
  const int b = orig >> 8;
  const int h = (orig >> 4) & 15;
  const int qt = orig & 15;

  const int LDQ = 3072;
  const int qg = qt * 64 + wid * 32 + ql;

  us8 qf[4];
  const unsigned short* qptr =
      qkv + (size_t)(b * 1024 + qg) * LDQ + h * 64 + 8 * hi;
#pragma unroll
  for (int db = 0; db < 4; ++db) qf[db] = *(const us8*)(qptr + db * 16);

  const float* pb = posT + (size_t)h * 3969;
  const int rb_q = ((qg >> 5) + 31) * 63 + (qg & 31) + 31 - 4 * hi;

  f32x16 oacc[2];
#pragma unroll
  for (int r = 0; r < 16; ++r) { oacc[0][r] = 0.f; oacc[1][r] = 0.f; }
  float mreg = -1e30f, lsum = 0.f;

  // staging maps (128 threads)
  const int ksr = tid >> 1;            // K row 0..63
  const int ksc = (tid & 1) * 32;      // K d-col base (4x us8 = 64B)
  const int vd0 = (tid & 15) * 4;      // V d cols
  const int vk0 = (tid >> 4) * 8;      // V k rows (8)

  const unsigned short* kbase = qkv + (size_t)(b * 1024) * LDQ + 1024 + h * 64;
  const unsigned short* vbase = qkv + (size_t)(b * 1024) * LDQ + 2048 + h * 64;

  us8 pk[4];
  us4 pvv[8];
#pragma unroll
  for (int j = 0; j < 4; ++j)
    pk[j] = *(const us8*)(kbase + (size_t)ksr * LDQ + ksc + j * 8);
#pragma unroll
  for (int j = 0; j < 8; ++j)
    pvv[j] = *(const us4*)(vbase + (size_t)(vk0 + j) * LDQ + vd0);

  for (int kt = 0; kt < 16; ++kt) {
    __syncthreads();
    {
      char* ksb = (char*)Ks;
      const int swr = (ksr & 7) << 4;
#pragma unroll
      for (int j = 0; j < 4; ++j)
        *(us8*)(ksb + ksr * 128 + (((ksc + j * 8) * 2) ^ swr)) = pk[j];
      char* vtb = (char*)Vt;
      const int cbase = vk0 << 1;  // byte offset of k-chunk (16B aligned)
#pragma unroll
      for (int u = 0; u < 4; ++u) {
        const int d = vd0 + u;
        const int addr = d * 128 + (cbase ^ ((d & 7) << 4));
        us4 lo, hi4;
        lo[0] = pvv[0][u]; lo[1] = pvv[1][u]; lo[2] = pvv[2][u]; lo[3] = pvv[3][u];
        hi4[0] = pvv[4][u]; hi4[1] = pvv[5][u]; hi4[2] = pvv[6][u]; hi4[3] = pvv[7][u];
        *(us4*)(vtb + addr) = lo;
        *(us4*)(vtb + addr + 8) = hi4;
      }
    }
    __syncthreads();

    // prefetch next tile
    if (kt < 15) {
      const unsigned short* kb2 = kbase + (size_t)((kt + 1) * 64) * LDQ;
      const unsigned short* vb2 = vbase + (size_t)((kt + 1) * 64) * LDQ;
#pragma unroll
      for (int j = 0; j < 4; ++j)
        pk[j] = *(const us8*)(kb2 + (size_t)ksr * LDQ + ksc + j * 8);
#pragma unroll
      for (int j = 0; j < 8; ++j)
        pvv[j] = *(const us4*)(vb2 + (size_t)(vk0 + j) * LDQ + vd0);
    }

    // S^T = K @ Q^T
    f32x16 st0, st1;
#pragma unroll
    for (int r = 0; r < 16; ++r) { st0[r] = 0.f; st1[r] = 0.f; }
    const char* ksb = (const char*)Ks;
    const int kswz = (ql & 7) << 4;
    __builtin_amdgcn_s_setprio(1);
#pragma unroll
    for (int db = 0; db < 4; ++db) {
      const int coff = (db * 32 + 16 * hi) ^ kswz;
      us8 kf0 = *(const us8*)(ksb + ql * 128 + coff);
      us8 kf1 = *(const us8*)(ksb + (32 + ql) * 128 + coff);
      st0 = mfma32(kf0, qf[db], st0);
      st1 = mfma32(kf1, qf[db], st1);
    }
    __builtin_amdgcn_s_setprio(0);

    // bias + scale; per-lane max tree
    float sv0[16], sv1[16];
    const float* pb0 = pb + (rb_q - 63 * (2 * kt));
    const float* pb1 = pb0 - 63;
    float mm[16];
#pragma unroll
    for (int r = 0; r < 16; ++r) {
      const int roff = (r & 3) + 8 * (r >> 2);
      float a = st0[r] * 0.125f + pb0[-roff];
      float c = st1[r] * 0.125f + pb1[-roff];
      sv0[r] = a;
      sv1[r] = c;
      mm[r] = fmaxf(a, c);
    }
#pragma unroll
    for (int w = 8; w >= 1; w >>= 1)
#pragma unroll
      for (int r = 0; r < w; ++r) mm[r] = fmaxf(mm[r], mm[r + w]);
    float pm = fmaxf(mm[0], __shfl_xor(mm[0], 32, 64));

    // defer-max: rescale only when tile max drifts past THR=8
    if (pm > mreg + 8.f) {
      const float f = __expf(mreg - pm);
      lsum *= f;
#pragma unroll
      for (int r = 0; r < 16; ++r) { oacc[0][r] *= f; oacc[1][r] *= f; }
      mreg = pm;
    }

    float ts[16];
#pragma unroll
    for (int r = 0; r < 16; ++r) {
      float e0 = __expf(sv0[r] - mreg);
      float e1 = __expf(sv1[r] - mreg);
      sv0[r] = e0;
      sv1[r] = e1;
      ts[r] = e0 + e1;
    }
#pragma unroll
    for (int w = 8; w >= 1; w >>= 1)
#pragma unroll
      for (int r = 0; r < w; ++r) ts[r] += ts[r + w];
    lsum += ts[0];

    // P fragments (cvt_pk + permlane32_swap) -> PV
    const char* vtb = (const char*)Vt;
    auto pvfrag = [&](const float* sv, int kb) {
      const int B0 = (kb & 1) * 8;
      unsigned a0 = pkbf(sv[B0 + 0], sv[B0 + 1]);
      unsigned a1 = pkbf(sv[B0 + 2], sv[B0 + 3]);
      unsigned b0 = pkbf(sv[B0 + 4], sv[B0 + 5]);
      unsigned b1 = pkbf(sv[B0 + 6], sv[B0 + 7]);
      pswap(a0, b0);
      pswap(a1, b1);
      union { us8 s; unsigned u[4]; } fu;
      fu.u[0] = a0; fu.u[1] = a1; fu.u[2] = b0; fu.u[3] = b1;
      const int coff = (kb * 32 + 16 * hi) ^ kswz;
      us8 vf0 = *(const us8*)(vtb + ql * 128 + coff);
      us8 vf1 = *(const us8*)(vtb + (32 + ql) * 128 + coff);
      __builtin_amdgcn_s_setprio(1);
      oacc[0] = mfma32(vf0, fu.s, oacc[0]);
      oacc[1] = mfma32(vf1, fu.s, oacc[1]);
      __builtin_amdgcn_s_setprio(0);
    };
    pvfrag(sv0, 0);
    pvfrag(sv0, 1);
    pvfrag(sv1, 2);
    pvfrag(sv1, 3);
  }

  lsum += __shfl_xor(lsum, 32, 64);
  const float inv = 1.f / lsum;
  unsigned short* orow = attnb + (size_t)(b * 1024 + qg) * 1024 + h * 64;
#pragma unroll
  for (int dm = 0; dm < 2; ++dm)
#pragma unroll
    for (int r = 0; r < 16; ++r) {
      const int d = dm * 32 + (r & 3) + 8 * (r >> 2) + 4 * hi;
      orow[d] = f2bf(oacc[dm][r] * inv);
    }
}

// ---------------------------------------------------------------------------
// Launcher
// ---------------------------------------------------------------------------
extern "C" void kernel_launch(void* const* d_in, const int* in_sizes, int n_in,
                              void* d_out, int out_size, void* d_ws,
                              size_t ws_size, hipStream_t stream) {
  const float* x = (const float*)d_in[0];
  const float* n1g = (const float*)d_in[1];
  const float* n1b = (const float*)d_in[2];
  const float* q_w = (const float*)d_in[3];
  const float* kv_w = (const float*)d_in[4];
  const float* proj_w = (const float*)d_in[5];
  const float* proj_b = (const float*)d_in[6];
  const float* pp_w = (const float*)d_in[7];
  const float* pp_b = (const float*)d_in[8];
  const float* ln1g = (const float*)d_in[9];
  const float* ln1b = (const float*)d_in[10];
  const float* lin1w = (const float*)d_in[11];
  const float* lin1b = (const float*)d_in[12];
  const float* ln2g = (const float*)d_in[13];
  const float* ln2b = (const float*)d_in[14];
  const float* lin2w = (const float*)d_in[15];
  const float* lin2b = (const float*)d_in[16];
  const float* ln3g = (const float*)d_in[17];
  const float* ln3b = (const float*)d_in[18];
  const float* lin3w = (const float*)d_in[19];
  const float* lin3b = (const float*)d_in[20];
  const float* n2g = (const float*)d_in[21];
  const float* n2b = (const float*)d_in[22];
  const float* fc1_w = (const float*)d_in[23];
  const float* fc1_b = (const float*)d_in[24];
  const float* fc2_w = (const float*)d_in[25];
  const float* fc2_b = (const float*)d_in[26];
  float* out = (float*)d_out;

  char* ws = (char*)d_ws;
  const size_t MB = 1024ull * 1024ull;
  unsigned short* qkvT = (unsigned short*)(ws + 0 * MB);
  unsigned short* projT = (unsigned short*)(ws + 6 * MB);
  unsigned short* fc1T = (unsigned short*)(ws + 8 * MB);
  unsigned short* fc2T = (unsigned short*)(ws + 16 * MB);
  unsigned short* xn = (unsigned short*)(ws + 24 * MB);
  unsigned short* qkv = (unsigned short*)(ws + 32 * MB);
  unsigned short* attnb = (unsigned short*)(ws + 56 * MB);
  float* x1 = (float*)(ws + 64 * MB);
  unsigned short* x2n = (unsigned short*)(ws + 80 * MB);
  unsigned short* hb = (unsigned short*)(ws + 88 * MB);
  float* posT = (float*)(ws + 120 * MB);

  // one launch: LN1 + pos MLP + 5 weight transposes
  prep_kernel<<<8161, 256, 0, stream>>>(
      x, n1g, n1b, xn, q_w, kv_w, proj_w, fc1_w, fc2_w, qkvT, projT, fc1T,
      fc2T, pp_w, pp_b, ln1g, ln1b, lin1w, lin1b, ln2g, ln2b, lin2w, lin2b,
      ln3g, ln3b, lin3w, lin3b, posT);

  // qkv: 128x128, BK=128 -> 768 blocks
  gemm_bt<128, 128, false, false, false, true, false>
      <<<dim3(32, 24), 256, 0, stream>>>(xn, qkvT, nullptr, nullptr, qkv,
                                         nullptr, 4096, 3072, 1024);

  attn_kernel<<<1024, 128, 0, stream>>>(qkv, posT, attnb);

  // proj: 64x128, BK=128 -> 512 blocks
  gemm_bt<64, 128, true, false, true, false, true>
      <<<dim3(64, 8), 256, 0, stream>>>(attnb, projT, proj_b, x, nullptr, x1,
                                        4096, 1024, 1024);

  ln_kernel<<<4096, 256, 0, stream>>>(x1, n2g, n2b, x2n);

  // fc1: 128x128, BK=128 -> 1024 blocks
  gemm_bt<128, 128, true, true, false, true, false>
      <<<dim3(32, 32), 256, 0, stream>>>(x2n, fc1T, fc1_b, nullptr, hb,
                                         nullptr, 4096, 4096, 1024);

  // fc2: 64x128, BK=128 -> 512 blocks
  gemm_bt<64, 128, true, false, true, false, true>
      <<<dim3(64, 8), 256, 0, stream>>>(hb, fc2T, fc2_b, x1, nullptr, out,
                                        4096, 1024, 4096);

  (void)in_sizes; (void)n_in; (void)out_size; (void)ws_size;
}